// Round 14
// baseline (10364.522 us; speedup 1.0000x reference)
//
#include <hip/hip_runtime.h>
#include <stdint.h>

// LSTM(relu) persistent kernel v14: B=64,S=1024,F=128,H=512.
// Validated base: XCD-local groups via HW_REG_XCC_ID, LDS-resident [U;W]^T
// (stride 648), v13 sign-tagged h words + epoch anti-runahead (replay-safe).
// New structure:
//  - PAIR-SPLIT: waves (0,1) compute tiles (0,1) with 2-way K-split (wave0:
//    h-k 0..7 + x-k 0,1; wave1: h-k 8..15 + x-k 2,3); waves (2,3) same for
//    tiles (2,3). Cross-wave reduce = 2-deep LDS flag handshake, ZERO
//    __syncthreads in the loop (was: 2 barriers + 4-way staging).
//  - COALESCED TAGGED PUBLISH: 3 shuffles gather a row's 4 units into one
//    lane -> ONE atomic u64 store per row (v13's 2B atomics caused 3x HBM
//    write amplification). Consumer poll loads these exact u64s: poll IS
//    the data (1 memory hop). Marker check: sign of low halfword per u64
//    (safe: u64 = one atomic producer store).
//  - epoch: LDS join (4 waves) -> 4th poster stores epoch=t; publisher gates
//    all epochs >= t-1 before overwriting gen t-2 (v13 semantics, 1-step
//    slack, snapshot loaded at step top).
// 256 wgs x 256 thr, ~91KB LDS -> exactly 1 wg/CU (XCD pigeonhole intact).

#define S_ 1024
#define F_ 128
#define H_ 512
#define G4_ 2048
#define KH 16           // h@U K-steps (512/32)
#define KDIM 640
#define LDKS 648        // padded LDS stride (shorts)
#define HB (64 * H_)    // one h buffer: 64 rows x 512 units (bf16, sign=marker)
#define SMASK8 0x8000800080008000ull
#define VMASK8 0x7FFF7FFF7FFF7FFFull

typedef __attribute__((ext_vector_type(8))) short short8;  // 8 x bf16
typedef __attribute__((ext_vector_type(4))) float f32x4;
typedef unsigned long long ull;

__device__ __forceinline__ unsigned short f2bf(float f) {
  union { float f; unsigned u; } v; v.f = f;
  unsigned u = v.u + 0x7fffu + ((v.u >> 16) & 1u);   // RNE
  return (unsigned short)(u >> 16);
}

__device__ __forceinline__ short8 pack2(f32x4 a, f32x4 b) {
  short8 r;
#pragma unroll
  for (int i = 0; i < 4; ++i) r[i] = (short)f2bf(a[i]);
#pragma unroll
  for (int i = 0; i < 4; ++i) r[4 + i] = (short)f2bf(b[i]);
  return r;
}

__global__ __launch_bounds__(256, 1) void lstm_pers(
    const float* __restrict__ x, const float* __restrict__ W,
    const float* __restrict__ U, const float* __restrict__ bias,
    float* __restrict__ out, unsigned int* ws_sync, unsigned short* hbuf) {

  __shared__ unsigned short V[64 * LDKS];   // 82944 B
  __shared__ f32x4 Rx[2][4][64];            // 8192 B partner-partial staging
  __shared__ unsigned lflag[4];             // pair handshake flags (monotonic)
  __shared__ unsigned jctr;                 // epoch join counter (monotonic)
  __shared__ int meta[2];

  const int tid  = threadIdx.x;
  const int w    = tid >> 6;           // wave 0..3; owns tile w
  const int lane = tid & 63;
  const int l15  = lane & 15;
  const int l4   = lane >> 4;
  const int koff = l4 * 8;

  // ---- physical XCD id + slot claim ----
  if (tid == 0) {
    unsigned int xcc;
    asm volatile("s_getreg_b32 %0, hwreg(20, 0, 4)" : "=s"(xcc));  // HW_REG_XCC_ID
    xcc &= 7;
    unsigned sv = atomicAdd(ws_sync + xcc * 32, 1u);   // 128B-spaced ctrs
    meta[0] = (int)xcc;
    meta[1] = (int)(sv & 31);
    jctr = 0u;
  }
  if (tid < 4) lflag[tid] = 0u;
  __syncthreads();
  const int xcc  = meta[0];
  const int slot = meta[1];

  // epoch line: ONE 128B line per group, 4B per slot
  unsigned int* eline = ws_sync + 256 + xcc * 32;
  unsigned int* myep  = eline + slot;
  unsigned int* epp   = eline + (lane & 31);

  const int u0    = slot * 16;       // 16 units per wg
  const int bbase = xcc * 8;         // 8 batch rows per group

  // ---- LDS fill (validated decomposition, stride 648) ----
  for (int idx = tid; idx < (64 * KDIM) / 4; idx += 256) {
    const int q4   = idx & 15;
    const int k    = idx >> 4;                // 0..639
    const int gate = q4 & 3;
    const int ul0  = (q4 >> 2) * 4;           // 0,4,8,12
    const int col  = gate * H_ + u0 + ul0;
    const float* src = (k < H_) ? (U + (size_t)k * G4_ + col)
                                : (W + (size_t)(k - H_) * G4_ + col);
    const f32x4 v4 = *(const f32x4*)src;
#pragma unroll
    for (int q = 0; q < 4; ++q) {
      const int ul = ul0 + q;
      const int cc = (ul >> 2) * 16 + (ul & 3) * 4 + gate;
      V[cc * LDKS + k] = f2bf(v4[q]);
    }
  }

  // wave w's gate bias for its OWN tile w: unit = u0 + w*4 + l4
  float bias_r[4];
#pragma unroll
  for (int g = 0; g < 4; ++g) bias_r[g] = bias[g * H_ + u0 + w * 4 + l4];

  __syncthreads();   // weights + flags ready; last barrier in the kernel

  const int brow   = bbase + (l15 & 7);     // rows duplicated for l15>=8
  const int myunit = u0 + w * 4 + l4;
  const int tA     = (w >> 1) * 2;          // pair's first tile
  const int khb    = (w & 1) * 8;           // my h k-step base (0 or 8)
  const int own    = w & 1;                 // own acc index within pair

  // x: this wave covers x-k-steps {(w&1)*2, (w&1)*2+1} (elements (w&1)*64 ..)
  const float* xrow = x + (size_t)brow * S_ * F_ + (w & 1) * 64 + koff;
  const unsigned short* hrowc = hbuf + (size_t)brow * H_ + koff;  // consumer base

  float cst = 0.f;

  // x(0) prefetch: 2 k-steps x (lo,hi) f32x4
  f32x4 xq0 = *(const f32x4*)(xrow);
  f32x4 xq1 = *(const f32x4*)(xrow + 4);
  f32x4 xq2 = *(const f32x4*)(xrow + 32);
  f32x4 xq3 = *(const f32x4*)(xrow + 36);

  for (int t = 0; t < S_; ++t) {
    // ---- epoch snapshot (early; checked at publish) ----
    unsigned ev = 0xFFFFFFFFu;
    if (t >= 2)
      ev = __hip_atomic_load(epp, __ATOMIC_RELAXED, __HIP_MEMORY_SCOPE_AGENT);

    // ---- x @ W: my 2 x-k-steps for both pair tiles ----
    f32x4 acc0 = {0.f, 0.f, 0.f, 0.f};   // tile tA
    f32x4 acc1 = {0.f, 0.f, 0.f, 0.f};   // tile tA+1
    {
      const short8 bx0 = pack2(xq0, xq1);
      const short8 bx1 = pack2(xq2, xq3);
      const int k0a = (KH + (w & 1) * 2) * 32 + koff;
      const int k0b = k0a + 32;
      const short8 aA0 = *(const short8*)&V[(tA * 16 + l15) * LDKS + k0a];
      const short8 aB0 = *(const short8*)&V[((tA + 1) * 16 + l15) * LDKS + k0a];
      const short8 aA1 = *(const short8*)&V[(tA * 16 + l15) * LDKS + k0b];
      const short8 aB1 = *(const short8*)&V[((tA + 1) * 16 + l15) * LDKS + k0b];
      acc0 = __builtin_amdgcn_mfma_f32_16x16x32_bf16(aA0, bx0, acc0, 0, 0, 0);
      acc1 = __builtin_amdgcn_mfma_f32_16x16x32_bf16(aB0, bx0, acc1, 0, 0, 0);
      acc0 = __builtin_amdgcn_mfma_f32_16x16x32_bf16(aA1, bx1, acc0, 0, 0, 0);
      acc1 = __builtin_amdgcn_mfma_f32_16x16x32_bf16(aB1, bx1, acc1, 0, 0, 0);
    }

    // ---- issue x(t+1) prefetch (completes under h@U) ----
    {
      const int tn = (t + 1 < S_) ? t + 1 : t;
      const float* xt = xrow + (size_t)tn * F_;
      xq0 = *(const f32x4*)(xt);
      xq1 = *(const f32x4*)(xt + 4);
      xq2 = *(const f32x4*)(xt + 32);
      xq3 = *(const f32x4*)(xt + 36);
    }

    // ---- tagged data-poll of my 8 h k-steps (the poll IS the data) ----
    if (t > 0) {
      const ull tm = (((((unsigned)(t - 1)) >> 1) & 1u) ^ 1u) ? SMASK8 : 0ull;
      const unsigned short* hr = hrowc + (size_t)(t & 1) * HB;
      ull hv_[16];
      while (true) {
#pragma unroll
        for (int i = 0; i < 8; ++i) {
          const ull* q = (const ull*)(hr + (khb + i) * 32);
          hv_[2 * i]     = __hip_atomic_load(q,     __ATOMIC_RELAXED, __HIP_MEMORY_SCOPE_AGENT);
          hv_[2 * i + 1] = __hip_atomic_load(q + 1, __ATOMIC_RELAXED, __HIP_MEMORY_SCOPE_AGENT);
        }
        ull orx = 0;
#pragma unroll
        for (int i = 0; i < 16; ++i) orx |= (hv_[i] ^ tm);
        if (__all((int)((orx & 0x8000ull) == 0)))   // low-hw sign per u64
          break;
      }
      // strip tags -> B-frags -> h@U MFMAs for both pair tiles
#pragma unroll
      for (int i = 0; i < 8; ++i) {
        union { ull u[2]; short8 s; } bb;
        bb.u[0] = hv_[2 * i] & VMASK8;
        bb.u[1] = hv_[2 * i + 1] & VMASK8;
        const int k0 = (khb + i) * 32 + koff;
        const short8 aA = *(const short8*)&V[(tA * 16 + l15) * LDKS + k0];
        const short8 aB = *(const short8*)&V[((tA + 1) * 16 + l15) * LDKS + k0];
        acc0 = __builtin_amdgcn_mfma_f32_16x16x32_bf16(aA, bb.s, acc0, 0, 0, 0);
        acc1 = __builtin_amdgcn_mfma_f32_16x16x32_bf16(aB, bb.s, acc1, 0, 0, 0);
      }
    }

    // ---- epoch join: wg finished reading gen t-1 -> 4th wave posts t ----
    if (lane == 0) {
      const unsigned old = atomicAdd(&jctr, 1u);
      if (old == 4u * (unsigned)t + 3u)
        __hip_atomic_store(myep, (unsigned)t, __ATOMIC_RELAXED, __HIP_MEMORY_SCOPE_AGENT);
    }

    // ---- pair handshake: swap partner-tile partials through LDS ----
    const f32x4 accO = own ? acc1 : acc0;   // my tile (w)
    const f32x4 accP = own ? acc0 : acc1;   // partner's tile (w^1)
    const int p = t & 1;
    Rx[p][w ^ 1][lane] = accP;
    __hip_atomic_store(&lflag[w], (unsigned)(t + 1),
                       __ATOMIC_RELEASE, __HIP_MEMORY_SCOPE_WORKGROUP);
    while (__hip_atomic_load(&lflag[w ^ 1], __ATOMIC_ACQUIRE,
                             __HIP_MEMORY_SCOPE_WORKGROUP) < (unsigned)(t + 1)) {}
    const f32x4 pp = Rx[p][w][lane];
    // Rx[p] reuse at t+2 is safe: partner's write at t+2 follows its data-poll
    // of gen t+1, which transitively follows every wg's reads+publishes of gen
    // t — which follow this read (all wgs consume all units every step).

    // ---- gates for (brow, myunit) ----
    const float z0 = bias_r[0] + accO[0] + pp[0];
    const float z1 = bias_r[1] + accO[1] + pp[1];
    const float z2 = bias_r[2] + accO[2] + pp[2];
    const float z3 = bias_r[3] + accO[3] + pp[3];
    const float ig = 1.f / (1.f + __expf(-z0));
    const float fg = 1.f / (1.f + __expf(-z1));
    const float gg = fmaxf(z2, 0.f);               // relu candidate
    const float og = 1.f / (1.f + __expf(-z3));
    const float cn = fg * cst + ig * gg;
    cst = cn;
    const float hv = og * fmaxf(cn, 0.f);          // relu output (>= 0)

    // ---- gather row's 4 units -> one tagged u64 per row ----
    const unsigned hb0 = (unsigned)f2bf(hv);
    const unsigned hb1 = (unsigned)__shfl((int)hb0, (lane & 7) + 16);
    const unsigned hb2 = (unsigned)__shfl((int)hb0, (lane & 7) + 32);
    const unsigned hb3 = (unsigned)__shfl((int)hb0, (lane & 7) + 48);
    const ull tagw = (((((unsigned)t) >> 1) & 1u) ^ 1u) ? SMASK8 : 0ull;
    const ull wrd = (ull)(hb0 & 0xFFFFu) | ((ull)(hb1 & 0xFFFFu) << 16) |
                    ((ull)(hb2 & 0xFFFFu) << 32) | ((ull)(hb3 & 0xFFFFu) << 48) | tagw;

    // ---- epoch gate: safe to overwrite gen t-2 ----
    if (t >= 2) {
      const unsigned tgt = (unsigned)(t - 1);
      while (!__all((int)(ev >= tgt)))
        ev = __hip_atomic_load(epp, __ATOMIC_RELAXED, __HIP_MEMORY_SCOPE_AGENT);
    }

    // ---- publish: ONE coalesced tagged u64 per row (lanes 0..7) ----
    if (lane < 8) {
      ull* dst = (ull*)(hbuf + (size_t)((t + 1) & 1) * HB +
                        (size_t)(bbase + lane) * H_ + u0 + w * 4);
      __hip_atomic_store(dst, wrd, __ATOMIC_RELAXED, __HIP_MEMORY_SCOPE_AGENT);
    }

    // ---- out store (off the publish path) ----
    if (l15 < 8)
      out[((size_t)brow * S_ + t) * H_ + myunit] = hv;
  }
}

extern "C" void kernel_launch(void* const* d_in, const int* in_sizes, int n_in,
                              void* d_out, int out_size, void* d_ws, size_t ws_size,
                              hipStream_t stream) {
  const float* x = (const float*)d_in[0];
  const float* W = (const float*)d_in[1];
  const float* U = (const float*)d_in[2];
  const float* b = (const float*)d_in[3];
  float* out = (float*)d_out;

  unsigned int*   ws_sync = (unsigned int*)d_ws;                    // ctrs(1KB) + epoch lines(1KB)
  unsigned short* hbuf    = (unsigned short*)((char*)d_ws + 32768); // 2 x 64 x 512 bf16 = 128KB

  // zero ctrs + epochs + BOTH tagged h buffers (markers must start invalid)
  hipMemsetAsync(d_ws, 0, 32768 + 2 * HB * sizeof(unsigned short), stream);

  lstm_pers<<<dim3(256), dim3(256), 0, stream>>>(x, W, U, b, out, ws_sync, hbuf);
}

// Round 15
// 2467.305 us; speedup vs baseline: 4.2007x; 4.2007x over previous
//
#include <hip/hip_runtime.h>
#include <stdint.h>

// LSTM(relu) persistent kernel v15: B=64,S=1024,F=128,H=512.
// = v7 (best passing, 2627us: XCD-local groups via HW_REG_XCC_ID, LDS-resident
// [U;W]^T bf16, 4-wave K-split, per-tile epilogue, x@W-before-poll, plain h
// stores + one atomic flag per wg) with ONE structural fix:
//   FLAGS SPREAD ONE PER 128B CACHE LINE (v7 packed all 32 into a single
//   line -> 32 per-step atomic stores serialized ~100-150cy each at the
//   coherence point ~= 3-4k cyc/step, the unexplained residual in v7's
//   step-time model; v1's single-address variant measured ~300cy/atomic).
//   Consumers gather-poll the 32 lines lane-parallel (lane i -> line i).
// Also: barrier3 -> LDS join counter (v12-proven): last-draining wave
// publishes the flag; 2 barriers per step. R stays single-buffered
// (read(t) < bar1(t+1) < write(t+1)); h overwrite safety unchanged
// (flag(t+1) transitively follows all reads of gen t-1).
// 256 wgs x 256 thr, ~99KB LDS -> exactly 1 wg/CU (XCD pigeonhole intact).

#define S_ 1024
#define F_ 128
#define H_ 512
#define G4_ 2048
#define KH 16           // h@U K-steps (512/32)
#define KDIM 640
#define LDKS 648        // padded LDS stride (shorts)
#define HB (64 * H_)    // one h buffer: 64 rows x 512 units (bf16)
#define FLW 32          // uints per flag line (128B)

typedef __attribute__((ext_vector_type(8))) short short8;  // 8 x bf16
typedef __attribute__((ext_vector_type(4))) float f32x4;
typedef unsigned long long ull;

__device__ __forceinline__ unsigned short f2bf(float f) {
  union { float f; unsigned u; } v; v.f = f;
  unsigned u = v.u + 0x7fffu + ((v.u >> 16) & 1u);   // RNE
  return (unsigned short)(u >> 16);
}

__device__ __forceinline__ short8 pack2(f32x4 a, f32x4 b) {
  short8 r;
#pragma unroll
  for (int i = 0; i < 4; ++i) r[i] = (short)f2bf(a[i]);
#pragma unroll
  for (int i = 0; i < 4; ++i) r[4 + i] = (short)f2bf(b[i]);
  return r;
}

__global__ __launch_bounds__(256, 1) void lstm_pers(
    const float* __restrict__ x, const float* __restrict__ W,
    const float* __restrict__ U, const float* __restrict__ bias,
    float* __restrict__ out, unsigned int* ws_sync, unsigned short* hbuf) {

  __shared__ unsigned short V[64 * LDKS];   // 82944 B
  __shared__ f32x4 R[4][4][64];             // 16384 B partial staging
  __shared__ int meta[2];
  __shared__ unsigned jctr;                 // join counter (monotonic)

  const int tid  = threadIdx.x;
  const int w    = tid >> 6;           // wave 0..3 (k-steps 4w..4w+3; tile w)
  const int lane = tid & 63;
  const int l15  = lane & 15;
  const int l4   = lane >> 4;
  const int koff = l4 * 8;

  // ---- physical XCD id + slot claim (robust group formation) ----
  if (tid == 0) {
    unsigned int xcc;
    asm volatile("s_getreg_b32 %0, hwreg(20, 0, 4)" : "=s"(xcc));  // HW_REG_XCC_ID
    xcc &= 7;
    unsigned sv = atomicAdd(ws_sync + xcc * 32, 1u);   // 128B-spaced ctrs
    meta[0] = (int)xcc;
    meta[1] = (int)(sv & 31);
    jctr = 0u;
  }
  __syncthreads();
  const int xcc  = meta[0];
  const int slot = meta[1];

  // flags: ONE 128B LINE PER WG (32 lines per group, 4KB/group)
  unsigned int* gflags = ws_sync + 256 + xcc * (32 * FLW);
  unsigned int* myflag = gflags + slot * FLW;
  unsigned int* pollp  = gflags + (lane & 31) * FLW;   // lane i -> line i

  const int u0    = slot * 16;       // 16 units per wg
  const int bbase = xcc * 8;         // 8 batch rows per group

  // ---- LDS fill (validated decomposition, stride 648) ----
  for (int idx = tid; idx < (64 * KDIM) / 4; idx += 256) {
    const int q4   = idx & 15;
    const int k    = idx >> 4;                // 0..639
    const int gate = q4 & 3;
    const int ul0  = (q4 >> 2) * 4;           // 0,4,8,12
    const int col  = gate * H_ + u0 + ul0;
    const float* src = (k < H_) ? (U + (size_t)k * G4_ + col)
                                : (W + (size_t)(k - H_) * G4_ + col);
    const f32x4 v4 = *(const f32x4*)src;
#pragma unroll
    for (int q = 0; q < 4; ++q) {
      const int ul = ul0 + q;
      const int cc = (ul >> 2) * 16 + (ul & 3) * 4 + gate;
      V[cc * LDKS + k] = f2bf(v4[q]);
    }
  }

  // wave w's gate bias for tile w: unit = u0 + w*4 + l4
  float bias_r[4];
#pragma unroll
  for (int g = 0; g < 4; ++g) bias_r[g] = bias[g * H_ + u0 + w * 4 + l4];

  __syncthreads();

  const int brow = bbase + (l15 & 7);   // rows duplicated for l15>=8
  const float* xrow = x + (size_t)brow * S_ * F_ + koff + w * 32;
  const unsigned short* hrow0 = hbuf + (size_t)brow * H_ + koff;
  const int myunit = u0 + w * 4 + l4;   // this lane's (row,unit) in tile w

  float cst = 0.f;                      // c-state of (brow, myunit)

  // preload x(0) slice for this wave
  f32x4 xa = *(const f32x4*)(xrow);
  f32x4 xb = *(const f32x4*)(xrow + 4);

  for (int t = 0; t < S_; ++t) {
    // ---- x @ W first (h-independent): hides poll latency below ----
    f32x4 acc[4];
#pragma unroll
    for (int tl = 0; tl < 4; ++tl) { acc[tl][0]=0.f; acc[tl][1]=0.f; acc[tl][2]=0.f; acc[tl][3]=0.f; }
    {
      const short8 bx = pack2(xa, xb);
      const int k0 = (KH + w) * 32 + koff;
#pragma unroll
      for (int tl = 0; tl < 4; ++tl) {
        const short8 a = *(const short8*)&V[(tl * 16 + l15) * LDKS + k0];
        acc[tl] = __builtin_amdgcn_mfma_f32_16x16x32_bf16(a, bx, acc[tl], 0, 0, 0);
      }
    }

    // ---- issue x(t+1) loads now; they complete under h@U ----
    {
      const int tn = (t + 1 < S_) ? t + 1 : t;
      const float* xt = xrow + (size_t)tn * F_;
      xa = *(const f32x4*)(xt);
      xb = *(const f32x4*)(xt + 4);
    }

    // ---- wave 0 gather-polls 32 flag LINES in parallel (no hot line) ----
    if (t > 0 && w == 0) {
      const unsigned tgt = (unsigned)t;
      while (true) {
        const unsigned v = __hip_atomic_load(pollp, __ATOMIC_RELAXED, __HIP_MEMORY_SCOPE_AGENT);
        if (__all((int)(v >= tgt))) break;
      }
    }
    __syncthreads();   // barrier1: h(t-1) safe for all waves

    // ---- my 4 h B-frags (k-steps 4w..4w+3) + h@U ----
    if (t > 0) {
      const unsigned short* hr = hrow0 + (size_t)(t & 1) * HB;
      short8 bh[4];
#pragma unroll
      for (int i = 0; i < 4; ++i) {
        union { ull u[2]; short8 s; } bb;
        const ull* hq = (const ull*)(hr + (4 * w + i) * 32);
        bb.u[0] = __hip_atomic_load(hq,     __ATOMIC_RELAXED, __HIP_MEMORY_SCOPE_AGENT);
        bb.u[1] = __hip_atomic_load(hq + 1, __ATOMIC_RELAXED, __HIP_MEMORY_SCOPE_AGENT);
        bh[i] = bb.s;
      }
#pragma unroll
      for (int i = 0; i < 4; ++i) {
        const int k0 = (4 * w + i) * 32 + koff;
#pragma unroll
        for (int tl = 0; tl < 4; ++tl) {
          const short8 a = *(const short8*)&V[(tl * 16 + l15) * LDKS + k0];
          acc[tl] = __builtin_amdgcn_mfma_f32_16x16x32_bf16(a, bh[i], acc[tl], 0, 0, 0);
        }
      }
    }

    // ---- stage partials; barrier2; wave w reduces ITS tile ----
#pragma unroll
    for (int tl = 0; tl < 4; ++tl) R[w][tl][lane] = acc[tl];
    __syncthreads();
    // single-buffered R safe: reads(t) precede bar1(t+1); writes(t+1) follow it.

    f32x4 z;
    {
      const f32x4 r0 = R[0][w][lane], r1 = R[1][w][lane],
                  r2 = R[2][w][lane], r3 = R[3][w][lane];
#pragma unroll
      for (int g = 0; g < 4; ++g)
        z[g] = bias_r[g] + r0[g] + r1[g] + r2[g] + r3[g];
    }

    // ---- gates for (brow, myunit) ----
    const float ig = 1.f / (1.f + __expf(-z[0]));
    const float fg = 1.f / (1.f + __expf(-z[1]));
    const float gg = fmaxf(z[2], 0.f);             // relu candidate
    const float og = 1.f / (1.f + __expf(-z[3]));
    const float cn = fg * cst + ig * gg;
    cst = cn;
    const float hv = og * fmaxf(cn, 0.f);          // relu output activation

    // ---- publish: plain h store; per-wave drain; LDS join; last wave flags ----
    if (l15 < 8)
      hbuf[(size_t)((t + 1) & 1) * HB + (size_t)brow * H_ + myunit] = f2bf(hv);
    asm volatile("s_waitcnt vmcnt(0)" ::: "memory");   // MY h slice acked

    if (lane == 0) {
      const unsigned old = atomicAdd(&jctr, 1u);
      if (old == 4u * (unsigned)t + 3u)   // last-draining wave of step t
        __hip_atomic_store(myflag, (unsigned)(t + 1),
                           __ATOMIC_RELAXED, __HIP_MEMORY_SCOPE_AGENT);
    }

    if (l15 < 8)
      out[((size_t)brow * S_ + t) * H_ + myunit] = hv;   // off the publish path
  }
}

extern "C" void kernel_launch(void* const* d_in, const int* in_sizes, int n_in,
                              void* d_out, int out_size, void* d_ws, size_t ws_size,
                              hipStream_t stream) {
  const float* x = (const float*)d_in[0];
  const float* W = (const float*)d_in[1];
  const float* U = (const float*)d_in[2];
  const float* b = (const float*)d_in[3];
  float* out = (float*)d_out;

  unsigned int*   ws_sync = (unsigned int*)d_ws;                    // ctrs(1KB) + flag lines(32KB)
  unsigned short* hbuf    = (unsigned short*)((char*)d_ws + 65536); // 2 x 64 x 512 bf16 = 128KB

  hipMemsetAsync(d_ws, 0, 65536, stream);   // zero slot ctrs + all flag lines

  lstm_pers<<<dim3(256), dim3(256), 0, stream>>>(x, W, U, b, out, ws_sync, hbuf);
}